// Round 6
// baseline (1770.979 us; speedup 1.0000x reference)
//
#include <hip/hip_runtime.h>

typedef unsigned short u16;
typedef unsigned int   u32;
typedef __attribute__((ext_vector_type(8))) short  short8;
typedef __attribute__((ext_vector_type(8))) unsigned short ushort8;
typedef __attribute__((ext_vector_type(4))) float  f32x4;

#define NT 1024      // timesteps
#define NN 33        // nodes
#define NE 97        // edges

__device__ __forceinline__ float b2f(u16 u){ return __uint_as_float(((u32)u)<<16); }
__device__ __forceinline__ u16 f2b(float f){
    u32 x = __float_as_uint(f);
    return (u16)((x + 0x7fffu + ((x>>16)&1u)) >> 16);
}
__device__ __forceinline__ float sigm(float x){ return 1.f/(1.f+__expf(-x)); }
__device__ __forceinline__ float tanh_(float x){ float e=__expf(2.f*x); return 1.f - 2.f/(e+1.f); }

// ---------------------------------------------------------------------------
// dtype detection: flag 0=bf16 inputs, 1=fp32 inputs.
// ---------------------------------------------------------------------------
__global__ void detect_kernel(const u32* g1_wl_raw, int* flag){
    if (threadIdx.x==0 && blockIdx.x==0){
        int hits=0;
        for (int k=0;k<256;k++){
            u32 w = g1_wl_raw[k];
            u32 e = (w>>7)&0xffu;
            if (e>=96u && e<=126u) hits++;
        }
        *flag = (hits>=160) ? 0 : 1;
    }
}

struct ConvArgs { const void* src[22]; int n[22]; int off[22]; };
__global__ void convert_kernel(ConvArgs a, const int* flag, u16* blob){
    bool isf32 = (*flag)!=0;
    int stride = gridDim.x*blockDim.x;
    for (int s=0;s<22;s++){
        int n=a.n[s]; const void* sp=a.src[s]; u16* dp=blob+a.off[s];
        for (int i=blockIdx.x*blockDim.x+threadIdx.x; i<n; i+=stride)
            dp[i] = isf32 ? f2b(((const float*)sp)[i]) : ((const u16*)sp)[i];
    }
}

// canonical blob element offsets
#define CX      0
#define CEA     67584
#define CG1WL   67880
#define CG1WR   68904
#define CG1WE   69928
#define CG1ATT  71464
#define CG1B    71976
#define CG2WL   72488
#define CG2WR   334632
#define CG2WE   596776
#define CG2ATT  598312
#define CG2B    598824
#define CL1WIH  599336
#define CL1WHH  9250088
#define CL1BIH  9315624
#define CL1BHH  9316136
#define CL2WIH  9316648
#define CL2WHH  9349416
#define CL2BIH  9365800
#define CL2BHH  9366056
#define CFCW    9366312
#define CFCB    9366568

// ---------------------------------------------------------------------------
// setup: CSR by dst + ep1/ep2 edge projections.
// ---------------------------------------------------------------------------
__global__ void setup_kernel(const int* ei, const u16* ea,
                             const u16* g1_we, const u16* g2_we,
                             int* csr, float* ep1, float* ep2)
{
    int tid = threadIdx.x;
    if (tid == 0) {
        int cnt[NN]; for (int n=0;n<NN;n++) cnt[n]=0;
        for (int e=0;e<NE;e++) cnt[ei[NE+e]]++;
        int off=0;
        for (int n=0;n<NN;n++){ csr[n]=off; off+=cnt[n]; }
        csr[NN]=off;
        int pos[NN]; for (int n=0;n<NN;n++) pos[n]=csr[n];
        for (int e=0;e<NE;e++){ int d=ei[NE+e]; csr[34+pos[d]]=e; pos[d]++; }
        for (int e=0;e<NE;e++){ csr[131+e]=ei[e]; csr[228+e]=ei[NE+e]; }
    }
    for (int i=tid; i<NE*512; i+=blockDim.x) {
        int e = i>>9, hc = i&511;
        float a0=b2f(ea[e*3]), a1=b2f(ea[e*3+1]), a2=b2f(ea[e*3+2]);
        ep1[i] = a0*b2f(g1_we[hc]) + a1*b2f(g1_we[512+hc]) + a2*b2f(g1_we[1024+hc]);
        ep2[i] = a0*b2f(g2_we[hc]) + a1*b2f(g2_we[512+hc]) + a2*b2f(g2_we[1024+hc]);
    }
}

// wlrt = [g2_wl^T ; g2_wr^T] (1024 x 512)
__global__ void wlrt_kernel(const u16* g2_wl, const u16* g2_wr, u16* wlrt)
{
    int i = blockIdx.x*256 + threadIdx.x;     // 262144 total
    int k = i>>9, c = i&511;
    wlrt[c*512 + k]        = g2_wl[i];
    wlrt[(c+512)*512 + k]  = g2_wr[i];
}

// ---------------------------------------------------------------------------
// GAT layer 1: one block per timestep.
// ---------------------------------------------------------------------------
__global__ __launch_bounds__(256) void gat1_kernel(
    const u16* x, const u16* g1_wl, const u16* g1_wr, const u16* g1_att,
    const u16* g1_b, const float* ep1, const int* csr, u16* h1)
{
    __shared__ float wl[2][512], wr[2][512], att[512], bias[512];
    __shared__ float xt[2*NN];
    __shared__ float logits[NE*8];
    __shared__ float mmax[NN*8], den[NN*8];
    __shared__ int s_off[NN+1], s_eid[NE], s_src[NE], s_dst[NE];
    int t = blockIdx.x, tid = threadIdx.x;

    for (int i=tid;i<512;i+=256){
        wl[0][i]=b2f(g1_wl[i]);      wl[1][i]=b2f(g1_wl[512+i]);
        wr[0][i]=b2f(g1_wr[i]);      wr[1][i]=b2f(g1_wr[512+i]);
        att[i]=b2f(g1_att[i]);       bias[i]=b2f(g1_b[i]);
    }
    for (int i=tid;i<2*NN;i+=256) xt[i]=b2f(x[t*(2*NN)+i]);
    if (tid<NN+1) s_off[tid]=csr[tid];
    for (int i=tid;i<NE;i+=256){ s_eid[i]=csr[34+i]; s_src[i]=csr[131+i]; s_dst[i]=csr[228+i]; }
    __syncthreads();

    for (int i=tid; i<NE*8; i+=256) {
        int e=i>>3, h=i&7;
        int s=s_src[e], d=s_dst[e];
        float xs0=xt[s*2], xs1=xt[s*2+1], xd0=xt[d*2], xd1=xt[d*2+1];
        const float* epp = ep1 + e*512 + h*64;
        float acc=0.f;
        #pragma unroll 8
        for (int c=0;c<64;c++){
            int hc=h*64+c;
            float v = xs0*wl[0][hc] + xs1*wl[1][hc]
                    + xd0*wr[0][hc] + xd1*wr[1][hc] + epp[c];
            v = v>0.f ? v : 0.2f*v;
            acc += att[hc]*v;
        }
        logits[i]=acc;
    }
    __syncthreads();
    for (int i=tid; i<NN*8; i+=256) {
        int n=i>>3, h=i&7;
        float m=-1e30f;
        for (int p=s_off[n]; p<s_off[n+1]; ++p){ float v=logits[s_eid[p]*8+h]; m=v>m?v:m; }
        float s=0.f;
        for (int p=s_off[n]; p<s_off[n+1]; ++p) s += __expf(logits[s_eid[p]*8+h]-m);
        mmax[i]=m; den[i]=s+1e-16f;
    }
    __syncthreads();
    for (int i=tid; i<NE*8; i+=256) {
        int h=i&7, d=s_dst[i>>3];
        logits[i] = __expf(logits[i]-mmax[d*8+h]) / den[d*8+h];
    }
    __syncthreads();
    for (int i=tid; i<NN*512; i+=256) {
        int n=i>>9, hc=i&511, h=hc>>6;
        float acc=0.f;
        for (int p=s_off[n]; p<s_off[n+1]; ++p){
            int e=s_eid[p]; int s=s_src[e];
            float xlv = xt[s*2]*wl[0][hc] + xt[s*2+1]*wl[1][hc];
            acc += logits[e*8+h]*xlv;
        }
        acc += bias[hc];
        acc = acc>0.f ? acc : __expf(acc)-1.f;
        h1[(size_t)(t*NN+n)*512 + hc] = f2b(acc);
    }
}

// ---------------------------------------------------------------------------
// NT GEMM: C[M,N] = A[M,K] * B[N,K]^T, bf16 in, fp32 acc. 128x128 tile.
// ---------------------------------------------------------------------------
__global__ __launch_bounds__(256) void gemm_nt(
    const u16* __restrict__ A, const u16* __restrict__ B, void* Cout,
    int M, int N, int K, int kChunk, int mode)
{
    __shared__ u16 lds_a[128*40];
    __shared__ u16 lds_b[128*40];
    const int nt = blockIdx.x, mt = blockIdx.y, kc = blockIdx.z;
    const int tid = threadIdx.x;
    const int wave = tid>>6, lane = tid&63;
    const int wm = (wave&1)*64, wn = (wave>>1)*64;
    const int l15 = lane&15, quad = lane>>4;
    const int srow = tid>>2, scol = (tid&3)*8;

    const u16* Ab = A + (size_t)mt*128*K;
    const u16* Bb = B + (size_t)nt*128*K;
    const int k0beg = kc*kChunk, k0end = k0beg + kChunk;

    f32x4 acc[4][4] = {};
    for (int k0 = k0beg; k0 < k0end; k0 += 32) {
        #pragma unroll
        for (int r = 0; r < 2; ++r) {
            int row = srow + r*64;
            *(ushort8*)&lds_a[row*40 + scol] = *(const ushort8*)&Ab[(size_t)row*K + k0 + scol];
            *(ushort8*)&lds_b[row*40 + scol] = *(const ushort8*)&Bb[(size_t)row*K + k0 + scol];
        }
        __syncthreads();
        short8 af[4], bfr[4];
        #pragma unroll
        for (int i=0;i<4;i++) af[i]  = *(const short8*)&lds_a[(wm + i*16 + l15)*40 + quad*8];
        #pragma unroll
        for (int j=0;j<4;j++) bfr[j] = *(const short8*)&lds_b[(wn + j*16 + l15)*40 + quad*8];
        #pragma unroll
        for (int i=0;i<4;i++)
            #pragma unroll
            for (int j=0;j<4;j++)
                acc[i][j] = __builtin_amdgcn_mfma_f32_16x16x32_bf16(af[i], bfr[j], acc[i][j], 0,0,0);
        __syncthreads();
    }
    if (mode == 0) {
        u16* Cb = (u16*)Cout;
        #pragma unroll
        for (int i=0;i<4;i++)
            #pragma unroll
            for (int j=0;j<4;j++)
                #pragma unroll
                for (int r=0;r<4;r++){
                    int row = mt*128 + wm + i*16 + quad*4 + r;
                    int col = nt*128 + wn + j*16 + l15;
                    Cb[(size_t)row*N + col] = f2b(acc[i][j][r]);
                }
    } else {
        float* Cb = (float*)Cout + (size_t)kc*M*N;
        #pragma unroll
        for (int i=0;i<4;i++)
            #pragma unroll
            for (int j=0;j<4;j++)
                #pragma unroll
                for (int r=0;r<4;r++){
                    int row = mt*128 + wm + i*16 + quad*4 + r;
                    int col = nt*128 + wn + j*16 + l15;
                    Cb[(size_t)row*N + col] = acc[i][j][r];
                }
    }
}

__global__ void reduce8_kernel(const float* part, float* out)
{
    int i = blockIdx.x*256 + threadIdx.x;   // 524288 total
    float s=0.f;
    #pragma unroll
    for (int k=0;k<8;k++) s += part[(size_t)k*524288 + i];
    out[i]=s;
}

// ---------------------------------------------------------------------------
// GAT layer 2 attention; writes h2 PERMUTED [n][t][c].
// ---------------------------------------------------------------------------
__global__ __launch_bounds__(256) void gat2_kernel(
    const u16* C, const u16* g2_att, const u16* g2_b, const float* ep2,
    const int* csr, u16* h2)
{
    __shared__ u16 xl[NN*512];
    __shared__ float att[512], bias[512];
    __shared__ float part[NE*8];
    __shared__ float logit[NE], alpha[NE], mm[NN], dd[NN];
    __shared__ int s_off[NN+1], s_eid[NE], s_src[NE], s_dst[NE];
    int t = blockIdx.x, tid = threadIdx.x;

    for (int i=tid;i<512;i+=256){ att[i]=b2f(g2_att[i]); bias[i]=b2f(g2_b[i]); }
    if (tid<NN+1) s_off[tid]=csr[tid];
    for (int i=tid;i<NE;i+=256){ s_eid[i]=csr[34+i]; s_src[i]=csr[131+i]; s_dst[i]=csr[228+i]; }
    for (int i=tid; i<NN*64; i+=256){
        int n=i>>6, q=i&63;
        *(ushort8*)&xl[n*512+q*8] = *(const ushort8*)&C[(size_t)(t*NN+n)*1024 + q*8];
    }
    __syncthreads();

    for (int i=tid; i<NE*8; i+=256){
        int e=i>>3, q=i&7;
        int s=s_src[e], d=s_dst[e];
        const u16* xrp = C + (size_t)(t*NN+d)*1024 + 512 + q*64;
        const float* epp = ep2 + e*512 + q*64;
        const u16* xlp = xl + s*512 + q*64;
        float acc=0.f;
        #pragma unroll 8
        for (int c=0;c<64;c++){
            float v = b2f(xlp[c]) + b2f(xrp[c]) + epp[c];
            v = v>0.f ? v : 0.2f*v;
            acc += att[q*64+c]*v;
        }
        part[i]=acc;
    }
    __syncthreads();
    for (int i=tid;i<NE;i+=256){
        float s=0.f;
        #pragma unroll
        for (int q=0;q<8;q++) s+=part[i*8+q];
        logit[i]=s;
    }
    __syncthreads();
    for (int i=tid;i<NN;i+=256){
        float m=-1e30f;
        for (int p=s_off[i];p<s_off[i+1];++p){ float v=logit[s_eid[p]]; m=v>m?v:m; }
        float s=0.f;
        for (int p=s_off[i];p<s_off[i+1];++p) s+=__expf(logit[s_eid[p]]-m);
        mm[i]=m; dd[i]=s+1e-16f;
    }
    __syncthreads();
    for (int i=tid;i<NE;i+=256) alpha[i]=__expf(logit[i]-mm[s_dst[i]])/dd[s_dst[i]];
    __syncthreads();
    for (int i=tid;i<NN*512;i+=256){
        int n=i>>9, c=i&511;
        float acc=0.f;
        for (int p=s_off[n];p<s_off[n+1];++p){ int e=s_eid[p]; acc += alpha[e]*b2f(xl[s_src[e]*512+c]); }
        acc += bias[c];
        acc = acc>0.f ? acc : __expf(acc)-1.f;
        h2[(size_t)n*524288 + (size_t)t*512 + c] = f2b(acc);
    }
}

// ---------------------------------------------------------------------------
// FUSED LSTM1+LSTM2+FC. One block, 512 threads = 8 waves.
// MFMA accumulation restructured: K-chunk OUTER, row-group INNER ->
// independent accumulators, no dependent MFMA chains (that was the R5 stall).
// ---------------------------------------------------------------------------
__global__ __launch_bounds__(512) void lstm_fused_kernel(
    const float* __restrict__ pre1,
    const u16* __restrict__ whh1, const u16* b1ih, const u16* b1hh,
    const u16* __restrict__ w2ih, const u16* __restrict__ w2hh,
    const u16* b2ih, const u16* b2hh,
    const u16* fc_w, const u16* fc_b, const int* flag, void* outv)
{
    __shared__ __align__(16) float pre_c[32*512];   // 64 KB chunk of pre1
    __shared__ __align__(16) u16 hb1[128];
    __shared__ __align__(16) u16 hb2[64];
    __shared__ __align__(16) float z_lds[768];      // [0,512)=z1, [512,768)=z2
    __shared__ float hf[64];
    const int tid = threadIdx.x;
    const int wave = tid>>6, lane = tid&63;
    const int l15 = lane&15, quad = lane>>4;
    const bool keep = (l15==0);
    const short8 zer = {0,0,0,0,0,0,0,0};
    const f32x4 fz = {0.f,0.f,0.f,0.f};
    const float4* p4g = (const float4*)pre1;
    float4* c4 = (float4*)pre_c;

    if (tid<128) hb1[tid]=0;
    if (wave==7) hb2[lane]=0;

    if (wave < 4) {
        // ---- lstm1 waves: z1 = Whh1(512x128) @ h1, wave w rows w*128.. ----
        short8 af[8][4];
        #pragma unroll
        for (int i=0;i<8;i++)
            #pragma unroll
            for (int c=0;c<4;c++)
                af[i][c] = *(const short8*)&whh1[(size_t)(wave*128 + i*16 + l15)*128 + c*32 + quad*8];
        float bz0=0,bz1=0,bz2=0,bz3=0, c1=0.f;
        if (tid<128){
            bz0 = b2f(b1ih[tid])     + b2f(b1hh[tid]);
            bz1 = b2f(b1ih[128+tid]) + b2f(b1hh[128+tid]);
            bz2 = b2f(b1ih[256+tid]) + b2f(b1hh[256+tid]);
            bz3 = b2f(b1ih[384+tid]) + b2f(b1hh[384+tid]);
        }
        __syncthreads();
        for (int k=0;k<=1024;k++){
            if (k<1024 && (k&31)==0){
                #pragma unroll
                for (int j=0;j<8;j++) c4[j*512+tid] = p4g[(size_t)k*128 + j*512 + tid];
                __syncthreads();
            }
            short8 bf[4];
            #pragma unroll
            for (int c=0;c<4;c++){
                short8 v = *(const short8*)&hb1[c*32 + quad*8];
                bf[c] = keep ? v : zer;
            }
            f32x4 acc[8];
            #pragma unroll
            for (int i=0;i<8;i++) acc[i]=fz;
            #pragma unroll
            for (int c=0;c<4;c++)
                #pragma unroll
                for (int i=0;i<8;i++)
                    acc[i] = __builtin_amdgcn_mfma_f32_16x16x32_bf16(af[i][c], bf[c], acc[i], 0,0,0);
            #pragma unroll
            for (int i=0;i<8;i++)
                if (keep) *(f32x4*)&z_lds[wave*128 + i*16 + quad*4] = acc[i];
            __syncthreads();
            if (k<1024 && tid<128){
                const float* pc = pre_c + (k&31)*512;
                float zi=z_lds[tid]    +pc[tid]    +bz0;
                float zf=z_lds[128+tid]+pc[128+tid]+bz1;
                float zg=z_lds[256+tid]+pc[256+tid]+bz2;
                float zo=z_lds[384+tid]+pc[384+tid]+bz3;
                c1 = sigm(zf)*c1 + sigm(zi)*tanh_(zg);
                float ho = sigm(zo)*tanh_(c1);
                hb1[tid] = f2b(ho);
            }
            __syncthreads();
        }
    } else {
        // ---- lstm2 waves: z2 = [W2ih|W2hh](256x192) @ [h1;h2] ----
        const int wv = wave-4;
        short8 af[4][6];
        #pragma unroll
        for (int i=0;i<4;i++){
            int r = wv*64 + i*16 + l15;
            #pragma unroll
            for (int c=0;c<4;c++)
                af[i][c] = *(const short8*)&w2ih[(size_t)r*128 + c*32 + quad*8];
            #pragma unroll
            for (int c=0;c<2;c++)
                af[i][4+c] = *(const short8*)&w2hh[(size_t)r*64 + c*32 + quad*8];
        }
        float bz0=0,bz1=0,bz2=0,bz3=0, c2=0.f;
        if (wave==7){
            bz0 = b2f(b2ih[lane])     + b2f(b2hh[lane]);
            bz1 = b2f(b2ih[64+lane])  + b2f(b2hh[64+lane]);
            bz2 = b2f(b2ih[128+lane]) + b2f(b2hh[128+lane]);
            bz3 = b2f(b2ih[192+lane]) + b2f(b2hh[192+lane]);
        }
        __syncthreads();
        for (int k=0;k<=1024;k++){
            if (k<1024 && (k&31)==0){
                #pragma unroll
                for (int j=0;j<8;j++) c4[j*512+tid] = p4g[(size_t)k*128 + j*512 + tid];
                __syncthreads();
            }
            short8 bf[6];
            #pragma unroll
            for (int c=0;c<4;c++){
                short8 v = *(const short8*)&hb1[c*32 + quad*8];
                bf[c] = keep ? v : zer;
            }
            #pragma unroll
            for (int c=0;c<2;c++){
                short8 v = *(const short8*)&hb2[c*32 + quad*8];
                bf[4+c] = keep ? v : zer;
            }
            f32x4 acc[4];
            #pragma unroll
            for (int i=0;i<4;i++) acc[i]=fz;
            #pragma unroll
            for (int c=0;c<6;c++)
                #pragma unroll
                for (int i=0;i<4;i++)
                    acc[i] = __builtin_amdgcn_mfma_f32_16x16x32_bf16(af[i][c], bf[c], acc[i], 0,0,0);
            #pragma unroll
            for (int i=0;i<4;i++)
                if (keep) *(f32x4*)&z_lds[512 + wv*64 + i*16 + quad*4] = acc[i];
            __syncthreads();
            if (k>=1 && wave==7){
                float zi=z_lds[512+lane]+bz0, zf=z_lds[576+lane]+bz1;
                float zg=z_lds[640+lane]+bz2, zo=z_lds[704+lane]+bz3;
                c2 = sigm(zf)*c2 + sigm(zi)*tanh_(zg);
                float ho = sigm(zo)*tanh_(c2);
                hb2[lane] = f2b(ho);
                hf[lane] = ho;
            }
            __syncthreads();
        }
    }
    __syncthreads();
    if (tid<4){
        float acc = b2f(fc_b[tid]);
        #pragma unroll
        for (int j=0;j<64;j++) acc += hf[j]*b2f(fc_w[tid*64+j]);
        if (*flag) ((float*)outv)[tid] = acc;
        else       ((u16*)outv)[tid]  = f2b(acc);
    }
}

// ---------------------------------------------------------------------------
extern "C" void kernel_launch(void* const* d_in, const int* in_sizes, int n_in,
                              void* d_out, int out_size, void* d_ws, size_t ws_size,
                              hipStream_t stream) {
    const int* ei = (const int*)d_in[1];
    char* ws = (char*)d_ws;

    const size_t o_blob = 0;
    const size_t o_h    = 18733184;
    const size_t o_C    = o_h    + 34603008;
    const size_t o_wlrt = o_C    + 69206016;
    const size_t o_ep1  = o_wlrt + 1048576;
    const size_t o_ep2  = o_ep1  + 198656;
    const size_t o_csr  = o_ep2  + 198656;
    const size_t o_pre1 = o_csr  + 2048;

    u16*   blob  = (u16*)(ws + o_blob);
    u16*   h_buf = (u16*)(ws + o_h);
    u16*   Cbuf  = (u16*)(ws + o_C);
    u16*   wlrt  = (u16*)(ws + o_wlrt);
    float* ep1   = (float*)(ws + o_ep1);
    float* ep2   = (float*)(ws + o_ep2);
    int*   csr   = (int*)(ws + o_csr);
    int*   flag  = csr + 400;
    float* pre1  = (float*)(ws + o_pre1);
    float* part  = (float*)(ws + o_C);

    detect_kernel<<<1,64,0,stream>>>((const u32*)d_in[3], flag);

    ConvArgs ca;
    const int blob_off[22] = {CX,CEA,CG1WL,CG1WR,CG1WE,CG1ATT,CG1B,
                              CG2WL,CG2WR,CG2WE,CG2ATT,CG2B,
                              CL1WIH,CL1WHH,CL1BIH,CL1BHH,
                              CL2WIH,CL2WHH,CL2BIH,CL2BHH,CFCW,CFCB};
    const int in_idx[22]   = {0,2,3,4,5,6,7,8,9,10,11,12,13,14,15,16,17,18,19,20,21,22};
    for (int s=0;s<22;s++){
        ca.src[s]=d_in[in_idx[s]]; ca.n[s]=in_sizes[in_idx[s]]; ca.off[s]=blob_off[s];
    }
    convert_kernel<<<2048,256,0,stream>>>(ca, flag, blob);

    setup_kernel<<<1,256,0,stream>>>(ei, blob+CEA, blob+CG1WE, blob+CG2WE, csr, ep1, ep2);
    wlrt_kernel<<<1024,256,0,stream>>>(blob+CG2WL, blob+CG2WR, wlrt);
    gat1_kernel<<<NT,256,0,stream>>>(blob+CX, blob+CG1WL, blob+CG1WR, blob+CG1ATT,
                                     blob+CG1B, ep1, csr, h_buf);
    gemm_nt<<<dim3(8,264,1),256,0,stream>>>(h_buf, wlrt, Cbuf, 33792, 1024, 512, 512, 0);
    gat2_kernel<<<NT,256,0,stream>>>(Cbuf, blob+CG2ATT, blob+CG2B, ep2, csr, h_buf);
    gemm_nt<<<dim3(4,8,8),256,0,stream>>>(h_buf, blob+CL1WIH, part, 1024, 512, 16896, 2112, 1);
    reduce8_kernel<<<2048,256,0,stream>>>(part, pre1);
    lstm_fused_kernel<<<1,512,0,stream>>>(pre1,
        blob+CL1WHH, blob+CL1BIH, blob+CL1BHH,
        blob+CL2WIH, blob+CL2WHH, blob+CL2BIH, blob+CL2BHH,
        blob+CFCW, blob+CFCB, flag, d_out);
}

// Round 7
// 1502.105 us; speedup vs baseline: 1.1790x; 1.1790x over previous
//
#include <hip/hip_runtime.h>

typedef unsigned short u16;
typedef unsigned int   u32;
typedef __attribute__((ext_vector_type(8))) short  short8;
typedef __attribute__((ext_vector_type(8))) unsigned short ushort8;
typedef __attribute__((ext_vector_type(4))) float  f32x4;

#define NT 1024      // timesteps
#define NN 33        // nodes
#define NE 97        // edges

__device__ __forceinline__ float b2f(u16 u){ return __uint_as_float(((u32)u)<<16); }
__device__ __forceinline__ u16 f2b(float f){
    u32 x = __float_as_uint(f);
    return (u16)((x + 0x7fffu + ((x>>16)&1u)) >> 16);
}
__device__ __forceinline__ float sigm(float x){ return 1.f/(1.f+__expf(-x)); }
__device__ __forceinline__ float tanh_(float x){ float e=__expf(2.f*x); return 1.f - 2.f/(e+1.f); }

// ---------------------------------------------------------------------------
// dtype detection: flag 0=bf16 inputs, 1=fp32 inputs.
// ---------------------------------------------------------------------------
__global__ void detect_kernel(const u32* g1_wl_raw, int* flag){
    if (threadIdx.x==0 && blockIdx.x==0){
        int hits=0;
        for (int k=0;k<256;k++){
            u32 w = g1_wl_raw[k];
            u32 e = (w>>7)&0xffu;
            if (e>=96u && e<=126u) hits++;
        }
        *flag = (hits>=160) ? 0 : 1;
    }
}

struct ConvArgs { const void* src[22]; int n[22]; int off[22]; };
__global__ void convert_kernel(ConvArgs a, const int* flag, u16* blob){
    bool isf32 = (*flag)!=0;
    int stride = gridDim.x*blockDim.x;
    for (int s=0;s<22;s++){
        int n=a.n[s]; const void* sp=a.src[s]; u16* dp=blob+a.off[s];
        for (int i=blockIdx.x*blockDim.x+threadIdx.x; i<n; i+=stride)
            dp[i] = isf32 ? f2b(((const float*)sp)[i]) : ((const u16*)sp)[i];
    }
}

// canonical blob element offsets
#define CX      0
#define CEA     67584
#define CG1WL   67880
#define CG1WR   68904
#define CG1WE   69928
#define CG1ATT  71464
#define CG1B    71976
#define CG2WL   72488
#define CG2WR   334632
#define CG2WE   596776
#define CG2ATT  598312
#define CG2B    598824
#define CL1WIH  599336
#define CL1WHH  9250088
#define CL1BIH  9315624
#define CL1BHH  9316136
#define CL2WIH  9316648
#define CL2WHH  9349416
#define CL2BIH  9365800
#define CL2BHH  9366056
#define CFCW    9366312
#define CFCB    9366568

// ---------------------------------------------------------------------------
// setup: CSR by dst + ep1/ep2 edge projections.
// ---------------------------------------------------------------------------
__global__ void setup_kernel(const int* ei, const u16* ea,
                             const u16* g1_we, const u16* g2_we,
                             int* csr, float* ep1, float* ep2)
{
    int tid = threadIdx.x;
    if (tid == 0) {
        int cnt[NN]; for (int n=0;n<NN;n++) cnt[n]=0;
        for (int e=0;e<NE;e++) cnt[ei[NE+e]]++;
        int off=0;
        for (int n=0;n<NN;n++){ csr[n]=off; off+=cnt[n]; }
        csr[NN]=off;
        int pos[NN]; for (int n=0;n<NN;n++) pos[n]=csr[n];
        for (int e=0;e<NE;e++){ int d=ei[NE+e]; csr[34+pos[d]]=e; pos[d]++; }
        for (int e=0;e<NE;e++){ csr[131+e]=ei[e]; csr[228+e]=ei[NE+e]; }
    }
    for (int i=tid; i<NE*512; i+=blockDim.x) {
        int e = i>>9, hc = i&511;
        float a0=b2f(ea[e*3]), a1=b2f(ea[e*3+1]), a2=b2f(ea[e*3+2]);
        ep1[i] = a0*b2f(g1_we[hc]) + a1*b2f(g1_we[512+hc]) + a2*b2f(g1_we[1024+hc]);
        ep2[i] = a0*b2f(g2_we[hc]) + a1*b2f(g2_we[512+hc]) + a2*b2f(g2_we[1024+hc]);
    }
}

// wlrt = [g2_wl^T ; g2_wr^T] (1024 x 512)
__global__ void wlrt_kernel(const u16* g2_wl, const u16* g2_wr, u16* wlrt)
{
    int i = blockIdx.x*256 + threadIdx.x;     // 262144 total
    int k = i>>9, c = i&511;
    wlrt[c*512 + k]        = g2_wl[i];
    wlrt[(c+512)*512 + k]  = g2_wr[i];
}

// ---------------------------------------------------------------------------
// permute LSTM weight rows to unit-major: r' = u*4+g  (orig r = g*H + u)
// w1p 512x128, w2ip 256x128, w2hp 256x64
// ---------------------------------------------------------------------------
__global__ void permw_kernel(const u16* w1hh, const u16* w2ih, const u16* w2hh,
                             u16* w1p, u16* w2ip, u16* w2hp)
{
    int i0 = blockIdx.x*256 + threadIdx.x;
    int stride = gridDim.x*256;
    for (int j=i0; j<65536; j+=stride){
        int r=j>>7, k=j&127, u=r>>2, g=r&3;
        w1p[j] = w1hh[(g*128+u)*128 + k];
    }
    for (int j=i0; j<32768; j+=stride){
        int r=j>>7, k=j&127, u=r>>2, g=r&3;
        w2ip[j] = w2ih[(g*64+u)*128 + k];
    }
    for (int j=i0; j<16384; j+=stride){
        int r=j>>6, k=j&63, u=r>>2, g=r&3;
        w2hp[j] = w2hh[(g*64+u)*64 + k];
    }
}

// ---------------------------------------------------------------------------
// GAT layer 1: one block per timestep.
// ---------------------------------------------------------------------------
__global__ __launch_bounds__(256) void gat1_kernel(
    const u16* x, const u16* g1_wl, const u16* g1_wr, const u16* g1_att,
    const u16* g1_b, const float* ep1, const int* csr, u16* h1)
{
    __shared__ float wl[2][512], wr[2][512], att[512], bias[512];
    __shared__ float xt[2*NN];
    __shared__ float logits[NE*8];
    __shared__ float mmax[NN*8], den[NN*8];
    __shared__ int s_off[NN+1], s_eid[NE], s_src[NE], s_dst[NE];
    int t = blockIdx.x, tid = threadIdx.x;

    for (int i=tid;i<512;i+=256){
        wl[0][i]=b2f(g1_wl[i]);      wl[1][i]=b2f(g1_wl[512+i]);
        wr[0][i]=b2f(g1_wr[i]);      wr[1][i]=b2f(g1_wr[512+i]);
        att[i]=b2f(g1_att[i]);       bias[i]=b2f(g1_b[i]);
    }
    for (int i=tid;i<2*NN;i+=256) xt[i]=b2f(x[t*(2*NN)+i]);
    if (tid<NN+1) s_off[tid]=csr[tid];
    for (int i=tid;i<NE;i+=256){ s_eid[i]=csr[34+i]; s_src[i]=csr[131+i]; s_dst[i]=csr[228+i]; }
    __syncthreads();

    for (int i=tid; i<NE*8; i+=256) {
        int e=i>>3, h=i&7;
        int s=s_src[e], d=s_dst[e];
        float xs0=xt[s*2], xs1=xt[s*2+1], xd0=xt[d*2], xd1=xt[d*2+1];
        const float* epp = ep1 + e*512 + h*64;
        float acc=0.f;
        #pragma unroll 8
        for (int c=0;c<64;c++){
            int hc=h*64+c;
            float v = xs0*wl[0][hc] + xs1*wl[1][hc]
                    + xd0*wr[0][hc] + xd1*wr[1][hc] + epp[c];
            v = v>0.f ? v : 0.2f*v;
            acc += att[hc]*v;
        }
        logits[i]=acc;
    }
    __syncthreads();
    for (int i=tid; i<NN*8; i+=256) {
        int n=i>>3, h=i&7;
        float m=-1e30f;
        for (int p=s_off[n]; p<s_off[n+1]; ++p){ float v=logits[s_eid[p]*8+h]; m=v>m?v:m; }
        float s=0.f;
        for (int p=s_off[n]; p<s_off[n+1]; ++p) s += __expf(logits[s_eid[p]*8+h]-m);
        mmax[i]=m; den[i]=s+1e-16f;
    }
    __syncthreads();
    for (int i=tid; i<NE*8; i+=256) {
        int h=i&7, d=s_dst[i>>3];
        logits[i] = __expf(logits[i]-mmax[d*8+h]) / den[d*8+h];
    }
    __syncthreads();
    for (int i=tid; i<NN*512; i+=256) {
        int n=i>>9, hc=i&511, h=hc>>6;
        float acc=0.f;
        for (int p=s_off[n]; p<s_off[n+1]; ++p){
            int e=s_eid[p]; int s=s_src[e];
            float xlv = xt[s*2]*wl[0][hc] + xt[s*2+1]*wl[1][hc];
            acc += logits[e*8+h]*xlv;
        }
        acc += bias[hc];
        acc = acc>0.f ? acc : __expf(acc)-1.f;
        h1[(size_t)(t*NN+n)*512 + hc] = f2b(acc);
    }
}

// ---------------------------------------------------------------------------
// NT GEMM: C[M,N] = A[M,K] * B[N,K]^T, bf16 in, fp32 acc. 128x128 tile.
// ---------------------------------------------------------------------------
__global__ __launch_bounds__(256) void gemm_nt(
    const u16* __restrict__ A, const u16* __restrict__ B, void* Cout,
    int M, int N, int K, int kChunk, int mode)
{
    __shared__ u16 lds_a[128*40];
    __shared__ u16 lds_b[128*40];
    const int nt = blockIdx.x, mt = blockIdx.y, kc = blockIdx.z;
    const int tid = threadIdx.x;
    const int wave = tid>>6, lane = tid&63;
    const int wm = (wave&1)*64, wn = (wave>>1)*64;
    const int l15 = lane&15, quad = lane>>4;
    const int srow = tid>>2, scol = (tid&3)*8;

    const u16* Ab = A + (size_t)mt*128*K;
    const u16* Bb = B + (size_t)nt*128*K;
    const int k0beg = kc*kChunk, k0end = k0beg + kChunk;

    f32x4 acc[4][4] = {};
    for (int k0 = k0beg; k0 < k0end; k0 += 32) {
        #pragma unroll
        for (int r = 0; r < 2; ++r) {
            int row = srow + r*64;
            *(ushort8*)&lds_a[row*40 + scol] = *(const ushort8*)&Ab[(size_t)row*K + k0 + scol];
            *(ushort8*)&lds_b[row*40 + scol] = *(const ushort8*)&Bb[(size_t)row*K + k0 + scol];
        }
        __syncthreads();
        short8 af[4], bfr[4];
        #pragma unroll
        for (int i=0;i<4;i++) af[i]  = *(const short8*)&lds_a[(wm + i*16 + l15)*40 + quad*8];
        #pragma unroll
        for (int j=0;j<4;j++) bfr[j] = *(const short8*)&lds_b[(wn + j*16 + l15)*40 + quad*8];
        #pragma unroll
        for (int i=0;i<4;i++)
            #pragma unroll
            for (int j=0;j<4;j++)
                acc[i][j] = __builtin_amdgcn_mfma_f32_16x16x32_bf16(af[i], bfr[j], acc[i][j], 0,0,0);
        __syncthreads();
    }
    if (mode == 0) {
        u16* Cb = (u16*)Cout;
        #pragma unroll
        for (int i=0;i<4;i++)
            #pragma unroll
            for (int j=0;j<4;j++)
                #pragma unroll
                for (int r=0;r<4;r++){
                    int row = mt*128 + wm + i*16 + quad*4 + r;
                    int col = nt*128 + wn + j*16 + l15;
                    Cb[(size_t)row*N + col] = f2b(acc[i][j][r]);
                }
    } else {
        float* Cb = (float*)Cout + (size_t)kc*M*N;
        #pragma unroll
        for (int i=0;i<4;i++)
            #pragma unroll
            for (int j=0;j<4;j++)
                #pragma unroll
                for (int r=0;r<4;r++){
                    int row = mt*128 + wm + i*16 + quad*4 + r;
                    int col = nt*128 + wn + j*16 + l15;
                    Cb[(size_t)row*N + col] = acc[i][j][r];
                }
    }
}

// reduce split-K partials AND permute columns to unit-major (r'=u*4+g)
__global__ void reduce8_kernel(const float* part, float* out)
{
    int i = blockIdx.x*256 + threadIdx.x;   // 524288 total: t*512+c (orig col c)
    float s=0.f;
    #pragma unroll
    for (int k=0;k<8;k++) s += part[(size_t)k*524288 + i];
    int t=i>>9, c=i&511;
    out[t*512 + ((c&127)<<2) + (c>>7)] = s;
}

// ---------------------------------------------------------------------------
// GAT layer 2 attention; writes h2 PERMUTED [n][t][c].
// ---------------------------------------------------------------------------
__global__ __launch_bounds__(256) void gat2_kernel(
    const u16* C, const u16* g2_att, const u16* g2_b, const float* ep2,
    const int* csr, u16* h2)
{
    __shared__ u16 xl[NN*512];
    __shared__ float att[512], bias[512];
    __shared__ float part[NE*8];
    __shared__ float logit[NE], alpha[NE], mm[NN], dd[NN];
    __shared__ int s_off[NN+1], s_eid[NE], s_src[NE], s_dst[NE];
    int t = blockIdx.x, tid = threadIdx.x;

    for (int i=tid;i<512;i+=256){ att[i]=b2f(g2_att[i]); bias[i]=b2f(g2_b[i]); }
    if (tid<NN+1) s_off[tid]=csr[tid];
    for (int i=tid;i<NE;i+=256){ s_eid[i]=csr[34+i]; s_src[i]=csr[131+i]; s_dst[i]=csr[228+i]; }
    for (int i=tid; i<NN*64; i+=256){
        int n=i>>6, q=i&63;
        *(ushort8*)&xl[n*512+q*8] = *(const ushort8*)&C[(size_t)(t*NN+n)*1024 + q*8];
    }
    __syncthreads();

    for (int i=tid; i<NE*8; i+=256){
        int e=i>>3, q=i&7;
        int s=s_src[e], d=s_dst[e];
        const u16* xrp = C + (size_t)(t*NN+d)*1024 + 512 + q*64;
        const float* epp = ep2 + e*512 + q*64;
        const u16* xlp = xl + s*512 + q*64;
        float acc=0.f;
        #pragma unroll 8
        for (int c=0;c<64;c++){
            float v = b2f(xlp[c]) + b2f(xrp[c]) + epp[c];
            v = v>0.f ? v : 0.2f*v;
            acc += att[q*64+c]*v;
        }
        part[i]=acc;
    }
    __syncthreads();
    for (int i=tid;i<NE;i+=256){
        float s=0.f;
        #pragma unroll
        for (int q=0;q<8;q++) s+=part[i*8+q];
        logit[i]=s;
    }
    __syncthreads();
    for (int i=tid;i<NN;i+=256){
        float m=-1e30f;
        for (int p=s_off[i];p<s_off[i+1];++p){ float v=logit[s_eid[p]]; m=v>m?v:m; }
        float s=0.f;
        for (int p=s_off[i];p<s_off[i+1];++p) s+=__expf(logit[s_eid[p]]-m);
        mm[i]=m; dd[i]=s+1e-16f;
    }
    __syncthreads();
    for (int i=tid;i<NE;i+=256) alpha[i]=__expf(logit[i]-mm[s_dst[i]])/dd[s_dst[i]];
    __syncthreads();
    for (int i=tid;i<NN*512;i+=256){
        int n=i>>9, c=i&511;
        float acc=0.f;
        for (int p=s_off[n];p<s_off[n+1];++p){ int e=s_eid[p]; acc += alpha[e]*b2f(xl[s_src[e]*512+c]); }
        acc += bias[c];
        acc = acc>0.f ? acc : __expf(acc)-1.f;
        h2[(size_t)n*524288 + (size_t)t*512 + c] = f2b(acc);
    }
}

// ---------------------------------------------------------------------------
// FUSED LSTM1+LSTM2+FC. 512 threads = 8 waves.
//  waves 0-3: z1 = W1hh'(512x128, unit-major rows) @ h1, replicated-B MFMA;
//             gates IN REGISTERS: lane l15=i, quad handles unit wave*32+i*4+quad
//  waves 4-7: z2 = [W2ih'|W2hh'](256x192) @ [h1;h2], one step behind lstm1
//  h double-buffered -> ONE barrier per step; pre1 (permuted cols) staged in
//  32-step LDS chunks. No z LDS round-trip, no per-step global traffic.
// ---------------------------------------------------------------------------
__global__ __launch_bounds__(512) void lstm_fused_kernel(
    const float* __restrict__ pre1p,
    const u16* __restrict__ w1p, const u16* b1ih, const u16* b1hh,
    const u16* __restrict__ w2ip, const u16* __restrict__ w2hp,
    const u16* b2ih, const u16* b2hh,
    const u16* fc_w, const u16* fc_b, const int* flag, void* outv)
{
    __shared__ __align__(16) float pre_c[32*512];   // 64 KB chunk of pre1p
    __shared__ __align__(16) u16 hb1[2][128];
    __shared__ __align__(16) u16 hb2[2][64];
    __shared__ float hf[64];
    const int tid = threadIdx.x;
    const int wave = tid>>6, lane = tid&63;
    const int l15 = lane&15, quad = lane>>4;
    const f32x4 fz = {0.f,0.f,0.f,0.f};
    const float4* p4g = (const float4*)pre1p;
    float4* c4 = (float4*)pre_c;

    if (tid<128) hb1[1][tid]=0;
    if (tid<64)  hb2[1][tid]=0;

    if (wave < 4) {
        // ---- lstm1 waves ----
        short8 af[8][4];
        #pragma unroll
        for (int i=0;i<8;i++)
            #pragma unroll
            for (int c=0;c<4;c++)
                af[i][c] = *(const short8*)&w1p[(size_t)(wave*128 + i*16 + l15)*128 + c*32 + quad*8];
        const int u = wave*32 + ((l15<8)?l15:0)*4 + quad;   // unit (valid l15<8)
        const float bz0 = b2f(b1ih[u])     + b2f(b1hh[u]);
        const float bz1 = b2f(b1ih[128+u]) + b2f(b1hh[128+u]);
        const float bz2 = b2f(b1ih[256+u]) + b2f(b1hh[256+u]);
        const float bz3 = b2f(b1ih[384+u]) + b2f(b1hh[384+u]);
        float c1 = 0.f;
        __syncthreads();
        for (int k=0;k<1025;k++){
            if (k<1024 && (k&31)==0){
                #pragma unroll
                for (int j=0;j<8;j++) c4[j*512+tid] = p4g[(size_t)k*128 + j*512 + tid];
                __syncthreads();
            }
            if (k<1024){
                float4 pf = {0.f,0.f,0.f,0.f};
                if (l15<8) pf = *(const float4*)&pre_c[(k&31)*512 + wave*128 + l15*16 + quad*4];
                const u16* hp = hb1[(k+1)&1];
                short8 b0 = *(const short8*)&hp[quad*8];
                short8 b1 = *(const short8*)&hp[32+quad*8];
                short8 b2 = *(const short8*)&hp[64+quad*8];
                short8 b3 = *(const short8*)&hp[96+quad*8];
                f32x4 acc[8];
                #pragma unroll
                for (int i=0;i<8;i++){
                    f32x4 a = __builtin_amdgcn_mfma_f32_16x16x32_bf16(af[i][0], b0, fz, 0,0,0);
                    a = __builtin_amdgcn_mfma_f32_16x16x32_bf16(af[i][1], b1, a, 0,0,0);
                    a = __builtin_amdgcn_mfma_f32_16x16x32_bf16(af[i][2], b2, a, 0,0,0);
                    a = __builtin_amdgcn_mfma_f32_16x16x32_bf16(af[i][3], b3, a, 0,0,0);
                    acc[i] = a;
                }
                f32x4 z = acc[0];
                #pragma unroll
                for (int i=1;i<8;i++) z = (l15==i) ? acc[i] : z;
                if (l15<8){
                    float zi = z[0]+pf.x+bz0;
                    float zf = z[1]+pf.y+bz1;
                    float zg = z[2]+pf.z+bz2;
                    float zo = z[3]+pf.w+bz3;
                    c1 = sigm(zf)*c1 + sigm(zi)*tanh_(zg);
                    float ho = sigm(zo)*tanh_(c1);
                    hb1[k&1][u] = f2b(ho);
                }
            }
            __syncthreads();
        }
    } else {
        // ---- lstm2 waves (one step behind) ----
        const int wv = wave-4;
        short8 af[4][6];
        #pragma unroll
        for (int i=0;i<4;i++){
            int r = wv*64 + i*16 + l15;
            #pragma unroll
            for (int c=0;c<4;c++)
                af[i][c] = *(const short8*)&w2ip[(size_t)r*128 + c*32 + quad*8];
            #pragma unroll
            for (int c=0;c<2;c++)
                af[i][4+c] = *(const short8*)&w2hp[(size_t)r*64 + c*32 + quad*8];
        }
        const int u2 = wv*16 + ((l15<4)?l15:0)*4 + quad;    // unit (valid l15<4)
        const float bz0 = b2f(b2ih[u2])     + b2f(b2hh[u2]);
        const float bz1 = b2f(b2ih[64+u2])  + b2f(b2hh[64+u2]);
        const float bz2 = b2f(b2ih[128+u2]) + b2f(b2hh[128+u2]);
        const float bz3 = b2f(b2ih[192+u2]) + b2f(b2hh[192+u2]);
        float c2s = 0.f;
        __syncthreads();
        for (int k=0;k<1025;k++){
            if (k<1024 && (k&31)==0){
                #pragma unroll
                for (int j=0;j<8;j++) c4[j*512+tid] = p4g[(size_t)k*128 + j*512 + tid];
                __syncthreads();
            }
            if (k>=1){
                const u16* hp1 = hb1[(k-1)&1];
                const u16* hp2 = hb2[k&1];
                short8 b0 = *(const short8*)&hp1[quad*8];
                short8 b1 = *(const short8*)&hp1[32+quad*8];
                short8 b2 = *(const short8*)&hp1[64+quad*8];
                short8 b3 = *(const short8*)&hp1[96+quad*8];
                short8 b4 = *(const short8*)&hp2[quad*8];
                short8 b5 = *(const short8*)&hp2[32+quad*8];
                f32x4 acc[4];
                #pragma unroll
                for (int i=0;i<4;i++){
                    f32x4 a = __builtin_amdgcn_mfma_f32_16x16x32_bf16(af[i][0], b0, fz, 0,0,0);
                    a = __builtin_amdgcn_mfma_f32_16x16x32_bf16(af[i][1], b1, a, 0,0,0);
                    a = __builtin_amdgcn_mfma_f32_16x16x32_bf16(af[i][2], b2, a, 0,0,0);
                    a = __builtin_amdgcn_mfma_f32_16x16x32_bf16(af[i][3], b3, a, 0,0,0);
                    a = __builtin_amdgcn_mfma_f32_16x16x32_bf16(af[i][4], b4, a, 0,0,0);
                    a = __builtin_amdgcn_mfma_f32_16x16x32_bf16(af[i][5], b5, a, 0,0,0);
                    acc[i] = a;
                }
                f32x4 z = acc[0];
                #pragma unroll
                for (int i=1;i<4;i++) z = (l15==i) ? acc[i] : z;
                if (l15<4){
                    float zi = z[0]+bz0;
                    float zf = z[1]+bz1;
                    float zg = z[2]+bz2;
                    float zo = z[3]+bz3;
                    c2s = sigm(zf)*c2s + sigm(zi)*tanh_(zg);
                    float ho = sigm(zo)*tanh_(c2s);
                    hb2[(k-1)&1][u2] = f2b(ho);
                    hf[u2] = ho;
                }
            }
            __syncthreads();
        }
    }
    __syncthreads();
    if (tid<4){
        float acc = b2f(fc_b[tid]);
        #pragma unroll
        for (int j=0;j<64;j++) acc += hf[j]*b2f(fc_w[tid*64+j]);
        if (*flag) ((float*)outv)[tid] = acc;
        else       ((u16*)outv)[tid]  = f2b(acc);
    }
}

// ---------------------------------------------------------------------------
extern "C" void kernel_launch(void* const* d_in, const int* in_sizes, int n_in,
                              void* d_out, int out_size, void* d_ws, size_t ws_size,
                              hipStream_t stream) {
    const int* ei = (const int*)d_in[1];
    char* ws = (char*)d_ws;

    const size_t o_blob = 0;
    const size_t o_h    = 18733184;
    const size_t o_C    = o_h    + 34603008;
    const size_t o_wlrt = o_C    + 69206016;
    const size_t o_ep1  = o_wlrt + 1048576;
    const size_t o_ep2  = o_ep1  + 198656;
    const size_t o_csr  = o_ep2  + 198656;
    const size_t o_pre1 = o_csr  + 2048;
    const size_t o_w1p  = o_pre1 + 2097152;
    const size_t o_w2ip = o_w1p  + 131072;
    const size_t o_w2hp = o_w2ip + 65536;

    u16*   blob  = (u16*)(ws + o_blob);
    u16*   h_buf = (u16*)(ws + o_h);
    u16*   Cbuf  = (u16*)(ws + o_C);
    u16*   wlrt  = (u16*)(ws + o_wlrt);
    float* ep1   = (float*)(ws + o_ep1);
    float* ep2   = (float*)(ws + o_ep2);
    int*   csr   = (int*)(ws + o_csr);
    int*   flag  = csr + 400;
    float* pre1  = (float*)(ws + o_pre1);
    u16*   w1p   = (u16*)(ws + o_w1p);
    u16*   w2ip  = (u16*)(ws + o_w2ip);
    u16*   w2hp  = (u16*)(ws + o_w2hp);
    float* part  = (float*)(ws + o_C);

    detect_kernel<<<1,64,0,stream>>>((const u32*)d_in[3], flag);

    ConvArgs ca;
    const int blob_off[22] = {CX,CEA,CG1WL,CG1WR,CG1WE,CG1ATT,CG1B,
                              CG2WL,CG2WR,CG2WE,CG2ATT,CG2B,
                              CL1WIH,CL1WHH,CL1BIH,CL1BHH,
                              CL2WIH,CL2WHH,CL2BIH,CL2BHH,CFCW,CFCB};
    const int in_idx[22]   = {0,2,3,4,5,6,7,8,9,10,11,12,13,14,15,16,17,18,19,20,21,22};
    for (int s=0;s<22;s++){
        ca.src[s]=d_in[in_idx[s]]; ca.n[s]=in_sizes[in_idx[s]]; ca.off[s]=blob_off[s];
    }
    convert_kernel<<<2048,256,0,stream>>>(ca, flag, blob);

    setup_kernel<<<1,256,0,stream>>>(ei, blob+CEA, blob+CG1WE, blob+CG2WE, csr, ep1, ep2);
    wlrt_kernel<<<1024,256,0,stream>>>(blob+CG2WL, blob+CG2WR, wlrt);
    permw_kernel<<<64,256,0,stream>>>(blob+CL1WHH, blob+CL2WIH, blob+CL2WHH, w1p, w2ip, w2hp);
    gat1_kernel<<<NT,256,0,stream>>>(blob+CX, blob+CG1WL, blob+CG1WR, blob+CG1ATT,
                                     blob+CG1B, ep1, csr, h_buf);
    gemm_nt<<<dim3(8,264,1),256,0,stream>>>(h_buf, wlrt, Cbuf, 33792, 1024, 512, 512, 0);
    gat2_kernel<<<NT,256,0,stream>>>(Cbuf, blob+CG2ATT, blob+CG2B, ep2, csr, h_buf);
    gemm_nt<<<dim3(4,8,8),256,0,stream>>>(h_buf, blob+CL1WIH, part, 1024, 512, 16896, 2112, 1);
    reduce8_kernel<<<2048,256,0,stream>>>(part, pre1);
    lstm_fused_kernel<<<1,512,0,stream>>>(pre1,
        w1p, blob+CL1BIH, blob+CL1BHH,
        w2ip, w2hp, blob+CL2BIH, blob+CL2BHH,
        blob+CFCW, blob+CFCB, flag, d_out);
}